// Round 13
// baseline (57.648 us; speedup 1.0000x reference)
//
#include <hip/hip_runtime.h>

#define B 16
#define N 1024
#define M 1024
#define TN 8
#define BPB (N / TN)             // 128 blocks per batch entry
#define NBLK (B * BPB)           // 2048 blocks
#define C2 64                    // band capacity per block

// ws float-index layout
#define WS_CNTR  0               // final counter (uint)
#define WS_RES   16              // per-b {sw, sc, se, cn, pose}, stride 8 -> 16..143
#define WS_PMAX  256             // per-block max, NBLK -> 256..2303
#define WS_BCNT  2304            // per-block band count (uint), NBLK -> 2304..4351
#define WS_PACC  4352            // per-block {sum_w,sum_cw,sum_ew,count} float4, NBLK
#define WS_BAND  12544           // per-block band triples {w, w*ce, w*ee}, NBLK*C2*3

#define NEG_INF (-3.402823466e+38f)

typedef float f4v __attribute__((ext_vector_type(4)));

// F row-major: F[i*3+l];  F = K^-T E K^-1, E = skew(t_n) R_gt
__device__ __forceinline__ void compute_F(const float* __restrict__ Rgp,
                                          const float* __restrict__ tg,
                                          const float* __restrict__ Km,
                                          float* F)
{
    float m00=Km[0], m01=Km[1], m02=Km[2];
    float m10=Km[3], m11=Km[4], m12=Km[5];
    float m20=Km[6], m21=Km[7], m22=Km[8];
    float c00 =  (m11*m22 - m12*m21), c01 = -(m10*m22 - m12*m20), c02 =  (m10*m21 - m11*m20);
    float c10 = -(m01*m22 - m02*m21), c11 =  (m00*m22 - m02*m20), c12 = -(m00*m21 - m01*m20);
    float c20 =  (m01*m12 - m02*m11), c21 = -(m00*m12 - m02*m10), c22 =  (m00*m11 - m01*m10);
    float id  = 1.f / (m00*c00 + m01*c01 + m02*c02);
    float Ki00 = c00*id, Ki01 = c10*id, Ki02 = c20*id;
    float Ki10 = c01*id, Ki11 = c11*id, Ki12 = c21*id;
    float Ki20 = c02*id, Ki21 = c12*id, Ki22 = c22*id;
    float inr = rsqrtf(tg[0]*tg[0] + tg[1]*tg[1] + tg[2]*tg[2]);
    float tx = tg[0]*inr, ty = tg[1]*inr, tz = tg[2]*inr;
    float Rg0=Rgp[0],Rg1=Rgp[1],Rg2=Rgp[2],Rg3=Rgp[3],Rg4=Rgp[4],Rg5=Rgp[5],Rg6=Rgp[6],Rg7=Rgp[7],Rg8=Rgp[8];
    float E00=-tz*Rg3+ty*Rg6, E01=-tz*Rg4+ty*Rg7, E02=-tz*Rg5+ty*Rg8;
    float E10= tz*Rg0-tx*Rg6, E11= tz*Rg1-tx*Rg7, E12= tz*Rg2-tx*Rg8;
    float E20=-ty*Rg0+tx*Rg3, E21=-ty*Rg1+tx*Rg4, E22=-ty*Rg2+tx*Rg5;
    float T00=E00*Ki00+E01*Ki10+E02*Ki20, T01=E00*Ki01+E01*Ki11+E02*Ki21, T02=E00*Ki02+E01*Ki12+E02*Ki22;
    float T10=E10*Ki00+E11*Ki10+E12*Ki20, T11=E10*Ki01+E11*Ki11+E12*Ki21, T12=E10*Ki02+E11*Ki12+E12*Ki22;
    float T20=E20*Ki00+E21*Ki10+E22*Ki20, T21=E20*Ki01+E21*Ki11+E22*Ki21, T22=E20*Ki02+E21*Ki12+E22*Ki22;
    F[0]=Ki00*T00+Ki10*T10+Ki20*T20; F[1]=Ki00*T01+Ki10*T11+Ki20*T21; F[2]=Ki00*T02+Ki10*T12+Ki20*T22;
    F[3]=Ki01*T00+Ki11*T10+Ki21*T20; F[4]=Ki01*T01+Ki11*T11+Ki21*T21; F[5]=Ki01*T02+Ki11*T12+Ki21*T22;
    F[6]=Ki02*T00+Ki12*T10+Ki22*T20; F[7]=Ki02*T01+Ki12*T11+Ki22*T21; F[8]=Ki02*T02+Ki12*T12+Ki22*T22;
}

// ---------- kernel 1: single full read of matches (nontemporal): max + local-thr sums + band
__launch_bounds__(256, 6)
__global__ void k1_fused(const float* __restrict__ matches,
                         const float* __restrict__ R_gt, const float* __restrict__ t_gt,
                         const float* __restrict__ Kin,
                         const float* __restrict__ kp1,  const float* __restrict__ kp2,
                         float* __restrict__ ws)
{
    const int bid = blockIdx.x;
    const int b = bid >> 7;
    const int row0 = (bid & 127) * TN;
    const int t = threadIdx.x;
    const int lane = t & 63, wv = t >> 6;
    if (bid == 0 && t == 0) ((unsigned int*)ws)[WS_CNTR] = 0u;

    __shared__ float4 sTP[TN];
    __shared__ float  sm[4];
    __shared__ float4 paccL[4];
    __shared__ int    wtot[4];

    // issue all 8 matches loads first — nontemporal (streamed once, no reuse)
    const f4v* m4 = (const f4v*)matches + ((long)b * N + row0) * (M/4) + t;
    f4v d[TN];
    #pragma unroll
    for (int n = 0; n < TN; ++n) d[n] = __builtin_nontemporal_load(m4 + n * (M/4));

    // per-row broadcast: T = (R_gt @ homo(kp1))[:2] and kp1
    const float* Rgp = R_gt + b * 9;
    if (t < TN) {
        float2 p = ((const float2*)kp1)[(long)b * N + row0 + t];
        sTP[t] = make_float4(Rgp[0]*p.x + Rgp[1]*p.y + Rgp[2],
                             Rgp[3]*p.x + Rgp[4]*p.y + Rgp[5], p.x, p.y);
    }

    // F + per-column factors (overlaps load latency)
    float F[9];
    compute_F(Rgp, t_gt + b*3, Kin + b*9, F);
    const float4* kp2v = (const float4*)(kp2 + (long)b * M * 2);
    float4 q0 = kp2v[2*t], q1 = kp2v[2*t + 1];
    float k2x[4] = {q0.x, q0.z, q1.x, q1.z};
    float k2y[4] = {q0.y, q0.w, q1.y, q1.w};
    float A0[4], A1[4], A2[4];
    #pragma unroll
    for (int j = 0; j < 4; ++j) {
        A0[j] = k2x[j]*F[0] + k2y[j]*F[3] + F[6];
        A1[j] = k2x[j]*F[1] + k2y[j]*F[4] + F[7];
        A2[j] = k2x[j]*F[2] + k2y[j]*F[5] + F[8];
    }

    // wave max
    float v = NEG_INF;
    #pragma unroll
    for (int n = 0; n < TN; ++n)
        v = fmaxf(v, fmaxf(fmaxf(d[n].x, d[n].y), fmaxf(d[n].z, d[n].w)));
    #pragma unroll
    for (int off = 32; off; off >>= 1) v = fmaxf(v, __shfl_down(v, off));
    if (lane == 0) sm[wv] = v;
    __syncthreads();                       // sTP + sm ready

    float bmax = fmaxf(fmaxf(sm[0], sm[1]), fmaxf(sm[2], sm[3]));
    if (t == 0) ws[WS_PMAX + bid] = bmax;
    float thr_b = 0.1f * bmax;
    float cap_b = 1.01f * thr_b;

    // sums at local threshold + band count
    float s_w = 0.f, s_c = 0.f, s_e = 0.f, s_n = 0.f;
    int bcnt = 0;
    #pragma unroll
    for (int n = 0; n < TN; ++n) {
        float4 tp = sTP[n];
        float mv[4] = {d[n].x, d[n].y, d[n].z, d[n].w};
        #pragma unroll
        for (int j = 0; j < 4; ++j) {
            float w = mv[j];
            bool pass = w > thr_b;
            float ww = pass ? w : 0.f;
            s_n += pass ? 1.f : 0.f;
            bcnt += (pass && w <= cap_b) ? 1 : 0;
            float dx = k2x[j] - tp.x, dy = k2y[j] - tp.y;
            float ce = sqrtf(dx*dx + dy*dy);
            float ee = fabsf(A0[j]*tp.z + A1[j]*tp.w + A2[j]);
            s_w += ww; s_c += ce*ww; s_e += ee*ww;
        }
    }
    // wave-reduce sums + wave-scan band count
    #pragma unroll
    for (int off = 32; off; off >>= 1) {
        s_w += __shfl_down(s_w, off);
        s_c += __shfl_down(s_c, off);
        s_e += __shfl_down(s_e, off);
        s_n += __shfl_down(s_n, off);
    }
    int incl = bcnt;
    #pragma unroll
    for (int off = 1; off < 64; off <<= 1) {
        int y = __shfl_up(incl, off);
        if (lane >= off) incl += y;
    }
    if (lane == 0)  paccL[wv] = make_float4(s_w, s_c, s_e, s_n);
    if (lane == 63) wtot[wv] = incl;
    __syncthreads();
    if (t == 0) {
        float4 r = paccL[0];
        #pragma unroll
        for (int i = 1; i < 4; ++i) { r.x += paccL[i].x; r.y += paccL[i].y; r.z += paccL[i].z; r.w += paccL[i].w; }
        ((float4*)(ws + WS_PACC))[bid] = r;
    }
    int pos = incl - bcnt;
    #pragma unroll
    for (int k = 0; k < 4; ++k) if (k < wv) pos += wtot[k];
    int total = wtot[0] + wtot[1] + wtot[2] + wtot[3];
    if (t == 0) ((unsigned int*)ws)[WS_BCNT + bid] = (unsigned int)total;

    if (total > 0 && total <= C2) {
        float* band = ws + WS_BAND + (long)bid * (C2 * 3);
        #pragma unroll
        for (int n = 0; n < TN; ++n) {
            float4 tp = sTP[n];
            float mv[4] = {d[n].x, d[n].y, d[n].z, d[n].w};
            #pragma unroll
            for (int j = 0; j < 4; ++j) {
                float w = mv[j];
                if (w > thr_b && w <= cap_b) {
                    float dx = k2x[j] - tp.x, dy = k2y[j] - tp.y;
                    float ce = sqrtf(dx*dx + dy*dy);
                    float ee = fabsf(A0[j]*tp.z + A1[j]*tp.w + A2[j]);
                    band[pos*3 + 0] = w;
                    band[pos*3 + 1] = ce * w;
                    band[pos*3 + 2] = ee * w;
                    ++pos;
                }
            }
        }
    }
}

// ---------- kernel 2: 16 blocks (one per b) — one-round metadata preload, R7 band walk,
//            parallel pose/combine, rare fallback.
__launch_bounds__(256)
__global__ void k2_perb(const float* __restrict__ matches,
                        const float* __restrict__ R_pred, const float* __restrict__ t_pred,
                        const float* __restrict__ R_gt,   const float* __restrict__ t_gt,
                        const float* __restrict__ Kin,
                        const float* __restrict__ kp1,    const float* __restrict__ kp2,
                        float* __restrict__ ws, float* __restrict__ out)
{
    const int b = blockIdx.x;
    const int t = threadIdx.x;
    const int lane = t & 63, wv = t >> 6;

    __shared__ float        sPM[BPB];
    __shared__ unsigned int sBC[BPB];
    __shared__ int          sBad[BPB];
    __shared__ float        sThr;
    __shared__ float4       sPacc[2];
    __shared__ float        sAcc4[4];
    __shared__ float        sPose;
    __shared__ int          sFlag[BPB];
    __shared__ int          sNFlag;
    __shared__ int          sLast;
    __shared__ float4       sTP[TN];

    if (t == 64) sNFlag = 0;

    // pose for this b (t==0, issued early — overlaps metadata preload below)
    if (t == 0) {
        const float* Rp = R_pred + b * 9;
        const float* Rq = R_gt   + b * 9;
        float trace = 0.f;
        #pragma unroll
        for (int i = 0; i < 9; ++i) trace += Rp[i] * Rq[i];
        float geo = fminf(fmaxf((trace - 1.f) * 0.5f, -1.f + 1e-7f), 1.f - 1e-7f);
        const float* tq = t_gt   + b * 3;
        const float* tp = t_pred + b * 3;
        float in2 = rsqrtf(tq[0]*tq[0] + tq[1]*tq[1] + tq[2]*tq[2]);
        float dotp = (tp[0]*tq[0] + tp[1]*tq[1] + tp[2]*tq[2]) * in2;
        sPose = (1.f - geo) + (1.f - dotp);
    }

    // ONE coalesced metadata round: PMAX, BCNT, PACC (independent loads in flight together)
    float4 myPacc = make_float4(0.f, 0.f, 0.f, 0.f);
    if (t < BPB) {
        sPM[t] = ws[WS_PMAX + b*BPB + t];
        sBC[t] = ((const unsigned int*)ws)[WS_BCNT + b*BPB + t];
        myPacc = ((const float4*)(ws + WS_PACC))[b*BPB + t];
    }
    __syncthreads();

    // true threshold
    if (t < 64) {
        float v = fmaxf(sPM[t], sPM[t + 64]);
        #pragma unroll
        for (int off = 32; off; off >>= 1) v = fmaxf(v, __shfl_down(v, off));
        if (t == 0) sThr = 0.1f * v;
    }
    __syncthreads();
    const float thr = sThr;

    // bad flags; zero bad bids' PACC (fallback re-adds their full sums)
    if (t < BPB) {
        bool bad = (sBC[t] > (unsigned)C2) || (thr > 1.01f * (0.1f * sPM[t]));
        sBad[t] = bad ? 1 : 0;
        if (bad) {
            int i = atomicAdd(&sNFlag, 1);
            sFlag[i] = t;
            myPacc = make_float4(0.f, 0.f, 0.f, 0.f);
        }
    }
    // PACC pre-reduce (waves 0-1 hold the 128 values)
    #pragma unroll
    for (int off = 32; off; off >>= 1) {
        myPacc.x += __shfl_down(myPacc.x, off);
        myPacc.y += __shfl_down(myPacc.y, off);
        myPacc.z += __shfl_down(myPacc.z, off);
        myPacc.w += __shfl_down(myPacc.w, off);
    }
    if (t < BPB && lane == 0) sPacc[wv] = myPacc;
    __syncthreads();
    if (t == 0) {
        sAcc4[0] = sPacc[0].x + sPacc[1].x;
        sAcc4[1] = sPacc[0].y + sPacc[1].y;
        sAcc4[2] = sPacc[0].z + sPacc[1].z;
        sAcc4[3] = sPacc[0].w + sPacc[1].w;
    }
    __syncthreads();

    // band walk: 2 threads per bid (R7-proven), metadata from LDS
    {
        int bidl = t >> 1;
        int half = t & 1;
        float s0 = 0.f, s1 = 0.f, s2 = 0.f, s3 = 0.f;
        if (!sBad[bidl]) {
            unsigned int bc = sBC[bidl];
            const float* band = ws + WS_BAND + (long)(b*BPB + bidl) * (C2 * 3);
            for (unsigned int k = half; k < bc; k += 2) {
                float w = band[k*3 + 0];
                if (!(w > thr)) { s0 += w; s1 += band[k*3 + 1]; s2 += band[k*3 + 2]; s3 += 1.f; }
            }
        }
        #pragma unroll
        for (int off = 32; off; off >>= 1) {
            s0 += __shfl_down(s0, off);
            s1 += __shfl_down(s1, off);
            s2 += __shfl_down(s2, off);
            s3 += __shfl_down(s3, off);
        }
        if (lane == 0) {
            atomicAdd(&sAcc4[0], -s0);
            atomicAdd(&sAcc4[1], -s1);
            atomicAdd(&sAcc4[2], -s2);
            atomicAdd(&sAcc4[3], -s3);
        }
    }
    __syncthreads();

    // fallback: full recompute of flagged tiles with true thr (normally 0)
    const int nflag = sNFlag;
    for (int f = 0; f < nflag; ++f) {
        __syncthreads();
        int rrow0 = sFlag[f] * TN;
        const float* Rgp = R_gt + b * 9;
        if (t < TN) {
            float2 p = ((const float2*)kp1)[(long)b * N + rrow0 + t];
            sTP[t] = make_float4(Rgp[0]*p.x + Rgp[1]*p.y + Rgp[2],
                                 Rgp[3]*p.x + Rgp[4]*p.y + Rgp[5], p.x, p.y);
        }
        float F[9];
        compute_F(Rgp, t_gt + b*3, Kin + b*9, F);
        const float4* kp2v = (const float4*)(kp2 + (long)b * M * 2);
        float4 q0 = kp2v[2*t], q1 = kp2v[2*t + 1];
        float k2x[4] = {q0.x, q0.z, q1.x, q1.z};
        float k2y[4] = {q0.y, q0.w, q1.y, q1.w};
        float A0[4], A1[4], A2[4];
        #pragma unroll
        for (int j = 0; j < 4; ++j) {
            A0[j] = k2x[j]*F[0] + k2y[j]*F[3] + F[6];
            A1[j] = k2x[j]*F[1] + k2y[j]*F[4] + F[7];
            A2[j] = k2x[j]*F[2] + k2y[j]*F[5] + F[8];
        }
        const float4* m4 = (const float4*)matches + ((long)b * N + rrow0) * (M/4) + t;
        float4 d[TN];
        #pragma unroll
        for (int n = 0; n < TN; ++n) d[n] = m4[n * (M/4)];
        __syncthreads();
        float s_w = 0.f, s_c = 0.f, s_e = 0.f, s_n = 0.f;
        #pragma unroll
        for (int n = 0; n < TN; ++n) {
            float4 tp = sTP[n];
            float mv[4] = {d[n].x, d[n].y, d[n].z, d[n].w};
            #pragma unroll
            for (int j = 0; j < 4; ++j) {
                float w = mv[j];
                bool pass = w > thr;
                float ww = pass ? w : 0.f;
                s_n += pass ? 1.f : 0.f;
                float dx = k2x[j] - tp.x, dy = k2y[j] - tp.y;
                float ce = sqrtf(dx*dx + dy*dy);
                float ee = fabsf(A0[j]*tp.z + A1[j]*tp.w + A2[j]);
                s_w += ww; s_c += ce*ww; s_e += ee*ww;
            }
        }
        #pragma unroll
        for (int off = 32; off; off >>= 1) {
            s_w += __shfl_down(s_w, off);
            s_c += __shfl_down(s_c, off);
            s_e += __shfl_down(s_e, off);
            s_n += __shfl_down(s_n, off);
        }
        if (lane == 0) {
            atomicAdd(&sAcc4[0], s_w);
            atomicAdd(&sAcc4[1], s_c);
            atomicAdd(&sAcc4[2], s_e);
            atomicAdd(&sAcc4[3], s_n);
        }
        __syncthreads();
    }
    __syncthreads();

    // per-b result; last of 16 blocks combines (16 fences/atomics total — proven cheap)
    if (t == 0) {
        float* res = ws + WS_RES + b * 8;
        res[0] = sAcc4[0]; res[1] = sAcc4[1]; res[2] = sAcc4[2]; res[3] = sAcc4[3];
        res[4] = sPose;
        __threadfence();
        unsigned int old = atomicAdd(((unsigned int*)ws) + WS_CNTR, 1u);
        sLast = (old == (unsigned int)(B - 1)) ? 1 : 0;
    }
    __syncthreads();
    if (!sLast) return;
    __threadfence();

    // parallel combine: lane i handles batch entry i
    if (wv == 0) {
        float po = 0.f, msv = 0.f, esv = 0.f, nvv = 0.f;
        if (lane < B) {
            const float* res = ws + WS_RES + lane * 8;
            float sw = res[0], sc = res[1], se = res[2], cn = res[3];
            po = res[4];
            if (cn >= 3.f) {
                nvv = 1.f;
                msv = sc / (sw + 1e-8f);
                esv = se / (sw + 1e-8f);
            }
        }
        #pragma unroll
        for (int off = 8; off; off >>= 1) {
            po  += __shfl_down(po,  off);
            msv += __shfl_down(msv, off);
            esv += __shfl_down(esv, off);
            nvv += __shfl_down(nvv, off);
        }
        if (lane == 0) {
            float match = nvv > 0.f ? msv / nvv : 0.f;
            float epi   = nvv > 0.f ? esv / nvv : 0.f;
            out[0] = po * (1.f / (float)B) + 0.5f * match + 0.1f * epi;
        }
    }
}

extern "C" void kernel_launch(void* const* d_in, const int* in_sizes, int n_in,
                              void* d_out, int out_size, void* d_ws, size_t ws_size,
                              hipStream_t stream) {
    const float* R_pred  = (const float*)d_in[0];
    const float* t_pred  = (const float*)d_in[1];
    const float* R_gt    = (const float*)d_in[2];
    const float* t_gt    = (const float*)d_in[3];
    const float* K       = (const float*)d_in[4];
    const float* kp1     = (const float*)d_in[5];
    const float* kp2     = (const float*)d_in[6];
    const float* matches = (const float*)d_in[7];
    float* out = (float*)d_out;
    float* ws  = (float*)d_ws;

    k1_fused<<<NBLK, 256, 0, stream>>>(matches, R_gt, t_gt, K, kp1, kp2, ws);
    k2_perb <<<B,    256, 0, stream>>>(matches, R_pred, t_pred, R_gt, t_gt, K, kp1, kp2, ws, out);
}

// Round 14
// 38.263 us; speedup vs baseline: 1.5066x; 1.5066x over previous
//
#include <hip/hip_runtime.h>

#define B 16
#define N 1024
#define M 1024
#define TN 8
#define BPB (N / TN)             // 128 blocks per batch entry
#define NBLK (B * BPB)           // 2048 blocks
#define C2 64                    // band capacity per block

// ws float-index layout
#define WS_CNTR  0               // final counter (uint)
#define WS_RES   16              // per-b {sw, sc, se, cn, pose}, stride 8 -> 16..143
#define WS_PMAX  256             // per-block max, NBLK -> 256..2303
#define WS_BCNT  2304            // per-block band count (uint), NBLK -> 2304..4351
#define WS_PACC  4352            // per-block {sum_w,sum_cw,sum_ew,count} float4, NBLK
#define WS_BAND  12544           // per-block band triples {w, w*ce, w*ee}, NBLK*C2*3

#define NEG_INF (-3.402823466e+38f)

// F row-major: F[i*3+l];  F = K^-T E K^-1, E = skew(t_n) R_gt
__device__ __forceinline__ void compute_F(const float* __restrict__ Rgp,
                                          const float* __restrict__ tg,
                                          const float* __restrict__ Km,
                                          float* F)
{
    float m00=Km[0], m01=Km[1], m02=Km[2];
    float m10=Km[3], m11=Km[4], m12=Km[5];
    float m20=Km[6], m21=Km[7], m22=Km[8];
    float c00 =  (m11*m22 - m12*m21), c01 = -(m10*m22 - m12*m20), c02 =  (m10*m21 - m11*m20);
    float c10 = -(m01*m22 - m02*m21), c11 =  (m00*m22 - m02*m20), c12 = -(m00*m21 - m01*m20);
    float c20 =  (m01*m12 - m02*m11), c21 = -(m00*m12 - m02*m10), c22 =  (m00*m11 - m01*m10);
    float id  = 1.f / (m00*c00 + m01*c01 + m02*c02);
    float Ki00 = c00*id, Ki01 = c10*id, Ki02 = c20*id;
    float Ki10 = c01*id, Ki11 = c11*id, Ki12 = c21*id;
    float Ki20 = c02*id, Ki21 = c12*id, Ki22 = c22*id;
    float inr = rsqrtf(tg[0]*tg[0] + tg[1]*tg[1] + tg[2]*tg[2]);
    float tx = tg[0]*inr, ty = tg[1]*inr, tz = tg[2]*inr;
    float Rg0=Rgp[0],Rg1=Rgp[1],Rg2=Rgp[2],Rg3=Rgp[3],Rg4=Rgp[4],Rg5=Rgp[5],Rg6=Rgp[6],Rg7=Rgp[7],Rg8=Rgp[8];
    float E00=-tz*Rg3+ty*Rg6, E01=-tz*Rg4+ty*Rg7, E02=-tz*Rg5+ty*Rg8;
    float E10= tz*Rg0-tx*Rg6, E11= tz*Rg1-tx*Rg7, E12= tz*Rg2-tx*Rg8;
    float E20=-ty*Rg0+tx*Rg3, E21=-ty*Rg1+tx*Rg4, E22=-ty*Rg2+tx*Rg5;
    float T00=E00*Ki00+E01*Ki10+E02*Ki20, T01=E00*Ki01+E01*Ki11+E02*Ki21, T02=E00*Ki02+E01*Ki12+E02*Ki22;
    float T10=E10*Ki00+E11*Ki10+E12*Ki20, T11=E10*Ki01+E11*Ki11+E12*Ki21, T12=E10*Ki02+E11*Ki12+E12*Ki22;
    float T20=E20*Ki00+E21*Ki10+E22*Ki20, T21=E20*Ki01+E21*Ki11+E22*Ki21, T22=E20*Ki02+E21*Ki12+E22*Ki22;
    F[0]=Ki00*T00+Ki10*T10+Ki20*T20; F[1]=Ki00*T01+Ki10*T11+Ki20*T21; F[2]=Ki00*T02+Ki10*T12+Ki20*T22;
    F[3]=Ki01*T00+Ki11*T10+Ki21*T20; F[4]=Ki01*T01+Ki11*T11+Ki21*T21; F[5]=Ki01*T02+Ki11*T12+Ki21*T22;
    F[6]=Ki02*T00+Ki12*T10+Ki22*T20; F[7]=Ki02*T01+Ki12*T11+Ki22*T21; F[8]=Ki02*T02+Ki12*T12+Ki22*T22;
}

// ---------- kernel 1: R7-proven — single full read: max + local-thr sums + band
__launch_bounds__(256, 4)
__global__ void k1_fused(const float* __restrict__ matches,
                         const float* __restrict__ R_gt, const float* __restrict__ t_gt,
                         const float* __restrict__ Kin,
                         const float* __restrict__ kp1,  const float* __restrict__ kp2,
                         float* __restrict__ ws)
{
    const int bid = blockIdx.x;
    const int b = bid >> 7;
    const int row0 = (bid & 127) * TN;
    const int t = threadIdx.x;
    const int lane = t & 63, wv = t >> 6;
    if (bid == 0 && t == 0) ((unsigned int*)ws)[WS_CNTR] = 0u;

    __shared__ float4 sTP[TN];
    __shared__ float  sm[4];
    __shared__ float4 paccL[4];
    __shared__ int    wtot[4];

    // issue all 8 matches loads first (32 VGPRs in flight)
    const float4* m4 = (const float4*)matches + ((long)b * N + row0) * (M/4) + t;
    float4 d[TN];
    #pragma unroll
    for (int n = 0; n < TN; ++n) d[n] = m4[n * (M/4)];

    // per-row broadcast: T = (R_gt @ homo(kp1))[:2] and kp1
    const float* Rgp = R_gt + b * 9;
    if (t < TN) {
        float2 p = ((const float2*)kp1)[(long)b * N + row0 + t];
        sTP[t] = make_float4(Rgp[0]*p.x + Rgp[1]*p.y + Rgp[2],
                             Rgp[3]*p.x + Rgp[4]*p.y + Rgp[5], p.x, p.y);
    }

    // F + per-column factors (overlaps load latency)
    float F[9];
    compute_F(Rgp, t_gt + b*3, Kin + b*9, F);
    const float4* kp2v = (const float4*)(kp2 + (long)b * M * 2);
    float4 q0 = kp2v[2*t], q1 = kp2v[2*t + 1];
    float k2x[4] = {q0.x, q0.z, q1.x, q1.z};
    float k2y[4] = {q0.y, q0.w, q1.y, q1.w};
    float A0[4], A1[4], A2[4];
    #pragma unroll
    for (int j = 0; j < 4; ++j) {
        A0[j] = k2x[j]*F[0] + k2y[j]*F[3] + F[6];
        A1[j] = k2x[j]*F[1] + k2y[j]*F[4] + F[7];
        A2[j] = k2x[j]*F[2] + k2y[j]*F[5] + F[8];
    }

    // wave max
    float v = NEG_INF;
    #pragma unroll
    for (int n = 0; n < TN; ++n)
        v = fmaxf(v, fmaxf(fmaxf(d[n].x, d[n].y), fmaxf(d[n].z, d[n].w)));
    #pragma unroll
    for (int off = 32; off; off >>= 1) v = fmaxf(v, __shfl_down(v, off));
    if (lane == 0) sm[wv] = v;
    __syncthreads();                       // sTP + sm ready

    float bmax = fmaxf(fmaxf(sm[0], sm[1]), fmaxf(sm[2], sm[3]));
    if (t == 0) ws[WS_PMAX + bid] = bmax;
    float thr_b = 0.1f * bmax;
    float cap_b = 1.01f * thr_b;

    // sums at local threshold + band count
    float s_w = 0.f, s_c = 0.f, s_e = 0.f, s_n = 0.f;
    int bcnt = 0;
    #pragma unroll
    for (int n = 0; n < TN; ++n) {
        float4 tp = sTP[n];
        float mv[4] = {d[n].x, d[n].y, d[n].z, d[n].w};
        #pragma unroll
        for (int j = 0; j < 4; ++j) {
            float w = mv[j];
            bool pass = w > thr_b;
            float ww = pass ? w : 0.f;
            s_n += pass ? 1.f : 0.f;
            bcnt += (pass && w <= cap_b) ? 1 : 0;
            float dx = k2x[j] - tp.x, dy = k2y[j] - tp.y;
            float ce = sqrtf(dx*dx + dy*dy);
            float ee = fabsf(A0[j]*tp.z + A1[j]*tp.w + A2[j]);
            s_w += ww; s_c += ce*ww; s_e += ee*ww;
        }
    }
    // wave-reduce sums + wave-scan band count
    #pragma unroll
    for (int off = 32; off; off >>= 1) {
        s_w += __shfl_down(s_w, off);
        s_c += __shfl_down(s_c, off);
        s_e += __shfl_down(s_e, off);
        s_n += __shfl_down(s_n, off);
    }
    int incl = bcnt;
    #pragma unroll
    for (int off = 1; off < 64; off <<= 1) {
        int y = __shfl_up(incl, off);
        if (lane >= off) incl += y;
    }
    if (lane == 0)  paccL[wv] = make_float4(s_w, s_c, s_e, s_n);
    if (lane == 63) wtot[wv] = incl;
    __syncthreads();
    if (t == 0) {
        float4 r = paccL[0];
        #pragma unroll
        for (int i = 1; i < 4; ++i) { r.x += paccL[i].x; r.y += paccL[i].y; r.z += paccL[i].z; r.w += paccL[i].w; }
        ((float4*)(ws + WS_PACC))[bid] = r;
    }
    int pos = incl - bcnt;
    #pragma unroll
    for (int k = 0; k < 4; ++k) if (k < wv) pos += wtot[k];
    int total = wtot[0] + wtot[1] + wtot[2] + wtot[3];
    if (t == 0) ((unsigned int*)ws)[WS_BCNT + bid] = (unsigned int)total;

    if (total > 0 && total <= C2) {
        float* band = ws + WS_BAND + (long)bid * (C2 * 3);
        #pragma unroll
        for (int n = 0; n < TN; ++n) {
            float4 tp = sTP[n];
            float mv[4] = {d[n].x, d[n].y, d[n].z, d[n].w};
            #pragma unroll
            for (int j = 0; j < 4; ++j) {
                float w = mv[j];
                if (w > thr_b && w <= cap_b) {
                    float dx = k2x[j] - tp.x, dy = k2y[j] - tp.y;
                    float ce = sqrtf(dx*dx + dy*dy);
                    float ee = fabsf(A0[j]*tp.z + A1[j]*tp.w + A2[j]);
                    band[pos*3 + 0] = w;
                    band[pos*3 + 1] = ce * w;
                    band[pos*3 + 2] = ee * w;
                    ++pos;
                }
            }
        }
    }
}

// ---------- kernel 2: 16 blocks (one per b) — one-round LDS metadata, R7 band walk,
//            parallel pose/combine, rare fallback.
__launch_bounds__(256)
__global__ void k2_perb(const float* __restrict__ matches,
                        const float* __restrict__ R_pred, const float* __restrict__ t_pred,
                        const float* __restrict__ R_gt,   const float* __restrict__ t_gt,
                        const float* __restrict__ Kin,
                        const float* __restrict__ kp1,    const float* __restrict__ kp2,
                        float* __restrict__ ws, float* __restrict__ out)
{
    const int b = blockIdx.x;
    const int t = threadIdx.x;
    const int lane = t & 63, wv = t >> 6;

    __shared__ float        sPM[BPB];
    __shared__ unsigned int sBC[BPB];
    __shared__ int          sBad[BPB];
    __shared__ float        sThr;
    __shared__ float4       sPacc[2];
    __shared__ float        sAcc4[4];
    __shared__ float        sPose;
    __shared__ int          sFlag[BPB];
    __shared__ int          sNFlag;
    __shared__ int          sLast;
    __shared__ float4       sTP[TN];

    if (t == 64) sNFlag = 0;

    // pose for this b (t==0, issued early — overlaps metadata preload below)
    if (t == 0) {
        const float* Rp = R_pred + b * 9;
        const float* Rq = R_gt   + b * 9;
        float trace = 0.f;
        #pragma unroll
        for (int i = 0; i < 9; ++i) trace += Rp[i] * Rq[i];
        float geo = fminf(fmaxf((trace - 1.f) * 0.5f, -1.f + 1e-7f), 1.f - 1e-7f);
        const float* tq = t_gt   + b * 3;
        const float* tp = t_pred + b * 3;
        float in2 = rsqrtf(tq[0]*tq[0] + tq[1]*tq[1] + tq[2]*tq[2]);
        float dotp = (tp[0]*tq[0] + tp[1]*tq[1] + tp[2]*tq[2]) * in2;
        sPose = (1.f - geo) + (1.f - dotp);
    }

    // ONE coalesced metadata round: PMAX, BCNT, PACC (independent loads in flight together)
    float4 myPacc = make_float4(0.f, 0.f, 0.f, 0.f);
    if (t < BPB) {
        sPM[t] = ws[WS_PMAX + b*BPB + t];
        sBC[t] = ((const unsigned int*)ws)[WS_BCNT + b*BPB + t];
        myPacc = ((const float4*)(ws + WS_PACC))[b*BPB + t];
    }
    __syncthreads();

    // true threshold
    if (t < 64) {
        float v = fmaxf(sPM[t], sPM[t + 64]);
        #pragma unroll
        for (int off = 32; off; off >>= 1) v = fmaxf(v, __shfl_down(v, off));
        if (t == 0) sThr = 0.1f * v;
    }
    __syncthreads();
    const float thr = sThr;

    // bad flags; zero bad bids' PACC (fallback re-adds their full sums)
    if (t < BPB) {
        bool bad = (sBC[t] > (unsigned)C2) || (thr > 1.01f * (0.1f * sPM[t]));
        sBad[t] = bad ? 1 : 0;
        if (bad) {
            int i = atomicAdd(&sNFlag, 1);
            sFlag[i] = t;
            myPacc = make_float4(0.f, 0.f, 0.f, 0.f);
        }
    }
    // PACC pre-reduce (waves 0-1 hold the 128 values)
    #pragma unroll
    for (int off = 32; off; off >>= 1) {
        myPacc.x += __shfl_down(myPacc.x, off);
        myPacc.y += __shfl_down(myPacc.y, off);
        myPacc.z += __shfl_down(myPacc.z, off);
        myPacc.w += __shfl_down(myPacc.w, off);
    }
    if (t < BPB && lane == 0) sPacc[wv] = myPacc;
    __syncthreads();
    if (t == 0) {
        sAcc4[0] = sPacc[0].x + sPacc[1].x;
        sAcc4[1] = sPacc[0].y + sPacc[1].y;
        sAcc4[2] = sPacc[0].z + sPacc[1].z;
        sAcc4[3] = sPacc[0].w + sPacc[1].w;
    }
    __syncthreads();

    // band walk: 2 threads per bid (R7-proven), metadata from LDS
    {
        int bidl = t >> 1;
        int half = t & 1;
        float s0 = 0.f, s1 = 0.f, s2 = 0.f, s3 = 0.f;
        if (!sBad[bidl]) {
            unsigned int bc = sBC[bidl];
            const float* band = ws + WS_BAND + (long)(b*BPB + bidl) * (C2 * 3);
            for (unsigned int k = half; k < bc; k += 2) {
                float w = band[k*3 + 0];
                if (!(w > thr)) { s0 += w; s1 += band[k*3 + 1]; s2 += band[k*3 + 2]; s3 += 1.f; }
            }
        }
        #pragma unroll
        for (int off = 32; off; off >>= 1) {
            s0 += __shfl_down(s0, off);
            s1 += __shfl_down(s1, off);
            s2 += __shfl_down(s2, off);
            s3 += __shfl_down(s3, off);
        }
        if (lane == 0) {
            atomicAdd(&sAcc4[0], -s0);
            atomicAdd(&sAcc4[1], -s1);
            atomicAdd(&sAcc4[2], -s2);
            atomicAdd(&sAcc4[3], -s3);
        }
    }
    __syncthreads();

    // fallback: full recompute of flagged tiles with true thr (normally 0)
    const int nflag = sNFlag;
    for (int f = 0; f < nflag; ++f) {
        __syncthreads();
        int rrow0 = sFlag[f] * TN;
        const float* Rgp = R_gt + b * 9;
        if (t < TN) {
            float2 p = ((const float2*)kp1)[(long)b * N + rrow0 + t];
            sTP[t] = make_float4(Rgp[0]*p.x + Rgp[1]*p.y + Rgp[2],
                                 Rgp[3]*p.x + Rgp[4]*p.y + Rgp[5], p.x, p.y);
        }
        float F[9];
        compute_F(Rgp, t_gt + b*3, Kin + b*9, F);
        const float4* kp2v = (const float4*)(kp2 + (long)b * M * 2);
        float4 q0 = kp2v[2*t], q1 = kp2v[2*t + 1];
        float k2x[4] = {q0.x, q0.z, q1.x, q1.z};
        float k2y[4] = {q0.y, q0.w, q1.y, q1.w};
        float A0[4], A1[4], A2[4];
        #pragma unroll
        for (int j = 0; j < 4; ++j) {
            A0[j] = k2x[j]*F[0] + k2y[j]*F[3] + F[6];
            A1[j] = k2x[j]*F[1] + k2y[j]*F[4] + F[7];
            A2[j] = k2x[j]*F[2] + k2y[j]*F[5] + F[8];
        }
        const float4* m4 = (const float4*)matches + ((long)b * N + rrow0) * (M/4) + t;
        float4 d[TN];
        #pragma unroll
        for (int n = 0; n < TN; ++n) d[n] = m4[n * (M/4)];
        __syncthreads();
        float s_w = 0.f, s_c = 0.f, s_e = 0.f, s_n = 0.f;
        #pragma unroll
        for (int n = 0; n < TN; ++n) {
            float4 tp = sTP[n];
            float mv[4] = {d[n].x, d[n].y, d[n].z, d[n].w};
            #pragma unroll
            for (int j = 0; j < 4; ++j) {
                float w = mv[j];
                bool pass = w > thr;
                float ww = pass ? w : 0.f;
                s_n += pass ? 1.f : 0.f;
                float dx = k2x[j] - tp.x, dy = k2y[j] - tp.y;
                float ce = sqrtf(dx*dx + dy*dy);
                float ee = fabsf(A0[j]*tp.z + A1[j]*tp.w + A2[j]);
                s_w += ww; s_c += ce*ww; s_e += ee*ww;
            }
        }
        #pragma unroll
        for (int off = 32; off; off >>= 1) {
            s_w += __shfl_down(s_w, off);
            s_c += __shfl_down(s_c, off);
            s_e += __shfl_down(s_e, off);
            s_n += __shfl_down(s_n, off);
        }
        if (lane == 0) {
            atomicAdd(&sAcc4[0], s_w);
            atomicAdd(&sAcc4[1], s_c);
            atomicAdd(&sAcc4[2], s_e);
            atomicAdd(&sAcc4[3], s_n);
        }
        __syncthreads();
    }
    __syncthreads();

    // per-b result; last of 16 blocks combines (16 fences/atomics total — proven cheap)
    if (t == 0) {
        float* res = ws + WS_RES + b * 8;
        res[0] = sAcc4[0]; res[1] = sAcc4[1]; res[2] = sAcc4[2]; res[3] = sAcc4[3];
        res[4] = sPose;
        __threadfence();
        unsigned int old = atomicAdd(((unsigned int*)ws) + WS_CNTR, 1u);
        sLast = (old == (unsigned int)(B - 1)) ? 1 : 0;
    }
    __syncthreads();
    if (!sLast) return;
    __threadfence();

    // parallel combine: lane i handles batch entry i
    if (wv == 0) {
        float po = 0.f, msv = 0.f, esv = 0.f, nvv = 0.f;
        if (lane < B) {
            const float* res = ws + WS_RES + lane * 8;
            float sw = res[0], sc = res[1], se = res[2], cn = res[3];
            po = res[4];
            if (cn >= 3.f) {
                nvv = 1.f;
                msv = sc / (sw + 1e-8f);
                esv = se / (sw + 1e-8f);
            }
        }
        #pragma unroll
        for (int off = 8; off; off >>= 1) {
            po  += __shfl_down(po,  off);
            msv += __shfl_down(msv, off);
            esv += __shfl_down(esv, off);
            nvv += __shfl_down(nvv, off);
        }
        if (lane == 0) {
            float match = nvv > 0.f ? msv / nvv : 0.f;
            float epi   = nvv > 0.f ? esv / nvv : 0.f;
            out[0] = po * (1.f / (float)B) + 0.5f * match + 0.1f * epi;
        }
    }
}

extern "C" void kernel_launch(void* const* d_in, const int* in_sizes, int n_in,
                              void* d_out, int out_size, void* d_ws, size_t ws_size,
                              hipStream_t stream) {
    const float* R_pred  = (const float*)d_in[0];
    const float* t_pred  = (const float*)d_in[1];
    const float* R_gt    = (const float*)d_in[2];
    const float* t_gt    = (const float*)d_in[3];
    const float* K       = (const float*)d_in[4];
    const float* kp1     = (const float*)d_in[5];
    const float* kp2     = (const float*)d_in[6];
    const float* matches = (const float*)d_in[7];
    float* out = (float*)d_out;
    float* ws  = (float*)d_ws;

    k1_fused<<<NBLK, 256, 0, stream>>>(matches, R_gt, t_gt, K, kp1, kp2, ws);
    k2_perb <<<B,    256, 0, stream>>>(matches, R_pred, t_pred, R_gt, t_gt, K, kp1, kp2, ws, out);
}